// Round 6
// baseline (258.152 us; speedup 1.0000x reference)
//
#include <hip/hip_runtime.h>

#define NQ 10000
#define BS 2
#define NV 19560
#define NH 8
#define HD 32
#define EMB 256

typedef __attribute__((ext_vector_type(8))) short bf16x8;
typedef __attribute__((ext_vector_type(4))) float f32x4;

__device__ __forceinline__ unsigned short f2bf(float x) {
    unsigned u = __float_as_uint(x);
    u += 0x7FFFu + ((u >> 16) & 1u);       // RNE
    return (unsigned short)(u >> 16);
}
__device__ __forceinline__ float bf2f(unsigned short h) {
    return __uint_as_float(((unsigned)h) << 16);
}

// ---------------------------------------------------------------------------
// Converters (memory-bound, hoisted out of GEMM main loops). [round-3 proven]
// ---------------------------------------------------------------------------
__global__ __launch_bounds__(256) void convert_val(const float* __restrict__ src,
                                                   ushort* __restrict__ dst) {
    size_t i = ((size_t)blockIdx.x * 256 + threadIdx.x) * 8;
    f32x4 a = *(const f32x4*)(src + i);
    f32x4 b = *(const f32x4*)(src + i + 4);
    ushort o[8];
    o[0]=f2bf(a.x); o[1]=f2bf(a.y); o[2]=f2bf(a.z); o[3]=f2bf(a.w);
    o[4]=f2bf(b.x); o[5]=f2bf(b.y); o[6]=f2bf(b.z); o[7]=f2bf(b.w);
    *(bf16x8*)(dst + i) = *(bf16x8*)o;
}

__global__ __launch_bounds__(256) void convert_q(const float* __restrict__ q,
                                                 const float* __restrict__ qp,
                                                 ushort* __restrict__ dst) {
    size_t i = ((size_t)blockIdx.x * 256 + threadIdx.x) * 8;
    f32x4 a = *(const f32x4*)(q + i)     + *(const f32x4*)(qp + i);
    f32x4 b = *(const f32x4*)(q + i + 4) + *(const f32x4*)(qp + i + 4);
    ushort o[8];
    o[0]=f2bf(a.x); o[1]=f2bf(a.y); o[2]=f2bf(a.z); o[3]=f2bf(a.w);
    o[4]=f2bf(b.x); o[5]=f2bf(b.y); o[6]=f2bf(b.z); o[7]=f2bf(b.w);
    *(bf16x8*)(dst + i) = *(bf16x8*)o;
}

// Transpose weights into Bt[n][k] bf16 (n: 0-255 W_val, 256-511 W_off,
// 512-639 W_attn) + concat biases. [round-3 proven, B-lo output dropped]
__global__ __launch_bounds__(256) void convert_W(
    const float* __restrict__ Wv, const float* __restrict__ Wo,
    const float* __restrict__ Wa, const float* __restrict__ bv,
    const float* __restrict__ bo, const float* __restrict__ ba,
    ushort* __restrict__ Bh, float* __restrict__ bias) {
    int n = blockIdx.x;      // 0..639
    int k = threadIdx.x;     // 0..255
    float x;
    if (n < 256)       x = Wv[k * 256 + n];
    else if (n < 512)  x = Wo[k * 256 + (n - 256)];
    else               x = Wa[k * 128 + (n - 512)];
    Bh[n * 256 + k] = f2bf(x);
    if (k == 0)
        bias[n] = (n < 256) ? bv[n] : (n < 512) ? bo[n - 256] : ba[n - 512];
}

// ---------------------------------------------------------------------------
// MFMA GEMM [round-3 proven structure, B-lo dropped]: C = A @ B + bias.
// A: M x 256 bf16. Bt: [n][k] bf16. 128x128 tile, BK=32, 4 waves 2x2.
// Global->LDS->fragment for BOTH operands (the HW-validated feed path).
// SPLITC=false: bf16 planar (b,h,pix,d) value store; true: fp32 off|attn.
// ---------------------------------------------------------------------------
template<bool SPLITC>
__global__ __launch_bounds__(256) void mfma_gemm2(
    const ushort* __restrict__ A, const ushort* __restrict__ Bh_g,
    const float* __restrict__ bias,
    ushort* __restrict__ Cv, float* __restrict__ C0, float* __restrict__ C1,
    int M)
{
    __shared__ short As[128][40], Bhs[128][40];  // pad 32->40

    const int tid = threadIdx.x;
    const int m0 = blockIdx.x * 128;
    const int n0 = blockIdx.y * 128;
    const int lane = tid & 63, wave = tid >> 6;
    const int wrow = (wave >> 1) * 64, wcol = (wave & 1) * 64;
    const int lr = lane & 15, quad = lane >> 4, lk = quad * 8;

    const int arow = tid >> 1;
    const int acol = (tid & 1) * 16;
    const bool aval = (m0 + arow) < M;
    const ushort* Ap  = A    + (size_t)(m0 + arow) * 256 + acol;
    const ushort* Bhp = Bh_g + (size_t)(n0 + arow) * 256 + acol;

    f32x4 acc[4][4] = {};

    for (int k0 = 0; k0 < 256; k0 += 32) {
        bf16x8 a0 = {}, a1 = {};
        if (aval) {
            a0 = *(const bf16x8*)(Ap + k0);
            a1 = *(const bf16x8*)(Ap + k0 + 8);
        }
        bf16x8 h0 = *(const bf16x8*)(Bhp + k0);
        bf16x8 h1 = *(const bf16x8*)(Bhp + k0 + 8);
        *(bf16x8*)&As[arow][acol]      = a0;
        *(bf16x8*)&As[arow][acol + 8]  = a1;
        *(bf16x8*)&Bhs[arow][acol]     = h0;
        *(bf16x8*)&Bhs[arow][acol + 8] = h1;
        __syncthreads();

        bf16x8 af[4], bhf[4];
        #pragma unroll
        for (int i = 0; i < 4; i++)
            af[i] = *(const bf16x8*)&As[wrow + i * 16 + lr][lk];
        #pragma unroll
        for (int j = 0; j < 4; j++)
            bhf[j] = *(const bf16x8*)&Bhs[wcol + j * 16 + lr][lk];
        #pragma unroll
        for (int i = 0; i < 4; i++)
            #pragma unroll
            for (int j = 0; j < 4; j++)
                acc[i][j] = __builtin_amdgcn_mfma_f32_16x16x32_bf16(af[i], bhf[j], acc[i][j], 0, 0, 0);
        __syncthreads();
    }

    #pragma unroll
    for (int j = 0; j < 4; j++) {
        int cc = wcol + j * 16 + lr;
        int col = n0 + cc;
        float bb = bias[col];
        #pragma unroll
        for (int i = 0; i < 4; i++) {
            int gmb = m0 + wrow + i * 16 + quad * 4;
            #pragma unroll
            for (int r = 0; r < 4; r++) {
                int gm = gmb + r;
                if (gm < M) {
                    float val = acc[i][j][r] + bb;
                    if (!SPLITC) {
                        int h = col >> 5, d = col & 31;
                        int b = (gm >= NV) ? 1 : 0;
                        int pix = gm - b * NV;
                        Cv[((size_t)(b * 8 + h) * NV + pix) * 32 + d] = f2bf(val);
                    } else {
                        if (col < 256) C0[(size_t)gm * 256 + col] = val;
                        else           C1[(size_t)gm * 128 + (col - 256)] = val;
                    }
                }
            }
        }
    }
}

// ---------------------------------------------------------------------------
// Fused softmax + location + bilinear gather. Block = TWO (b,q), 256 threads.
// Phase 1: thread = one (q,h,l,p) point: softmax over 16 logits (shuffle w16),
// pixel coords x=ref*W+off-0.5, clamped corner offsets + validity-premultiplied
// weights -> LDS. Phase 2: 16 lanes per (q,h), lane = channel pair (dword
// gather of 2 bf16), scalar fp32 accumulation.
// ---------------------------------------------------------------------------
__global__ __launch_bounds__(256) void sample3(
    const ushort* __restrict__ v, const float* __restrict__ off,
    const float* __restrict__ attn, const float* __restrict__ refp,
    float* __restrict__ out)
{
    __shared__ int   s_off[256][5];
    __shared__ float s_w[256][5];

    const int bq0 = blockIdx.x * 2;
    const int t = threadIdx.x;

    {
        const int bq = bq0 + (t >> 7);
        const int b = (bq >= NQ) ? 1 : 0;
        const int i = t & 127;
        const int h = i >> 4, l = (i >> 2) & 3, p = i & 3;

        float logit = attn[(size_t)bq * 128 + i];
        float mx = logit;
        #pragma unroll
        for (int m = 1; m < 16; m <<= 1) mx = fmaxf(mx, __shfl_xor(mx, m, 16));
        float e = __expf(logit - mx);
        float s = e;
        #pragma unroll
        for (int m = 1; m < 16; m <<= 1) s += __shfl_xor(s, m, 16);
        float w = e / s;

        const float Wf[4] = {160.f, 80.f, 40.f, 20.f};
        const float Hf[4] = {92.f, 46.f, 23.f, 12.f};
        const int   Wi[4] = {160, 80, 40, 20};
        const int   Hi[4] = {92, 46, 23, 12};
        const int   st[4] = {0, 14720, 18400, 19320};

        float ox = off[(size_t)bq * 256 + h * 32 + l * 8 + p * 2];
        float oy = off[(size_t)bq * 256 + h * 32 + l * 8 + p * 2 + 1];
        float rx = refp[(size_t)bq * 8 + p * 2];
        float ry = refp[(size_t)bq * 8 + p * 2 + 1];
        float x = rx * Wf[l] + ox - 0.5f;
        float y = ry * Hf[l] + oy - 0.5f;
        float x0f = floorf(x), y0f = floorf(y);
        float wx1 = x - x0f, wy1 = y - y0f;
        float wx0 = 1.f - wx1, wy0 = 1.f - wy1;
        int x0 = (int)x0f, y0 = (int)y0f;
        const int W = Wi[l], H = Hi[l];
        float mx0 = ((unsigned)x0       < (unsigned)W) ? 1.f : 0.f;
        float mx1 = ((unsigned)(x0 + 1) < (unsigned)W) ? 1.f : 0.f;
        float my0 = ((unsigned)y0       < (unsigned)H) ? 1.f : 0.f;
        float my1 = ((unsigned)(y0 + 1) < (unsigned)H) ? 1.f : 0.f;
        int xc0 = min(max(x0, 0), W - 1);
        int xc1 = min(max(x0 + 1, 0), W - 1);
        int yc0 = min(max(y0, 0), H - 1);
        int yc1 = min(max(y0 + 1, 0), H - 1);
        int base = ((b * 8 + h) * NV + st[l]) * 32;
        s_off[t][0] = base + (yc0 * W + xc0) * 32;
        s_off[t][1] = base + (yc0 * W + xc1) * 32;
        s_off[t][2] = base + (yc1 * W + xc0) * 32;
        s_off[t][3] = base + (yc1 * W + xc1) * 32;
        s_w[t][0] = w * wy0 * wx0 * my0 * mx0;
        s_w[t][1] = w * wy0 * wx1 * my0 * mx1;
        s_w[t][2] = w * wy1 * wx0 * my1 * mx0;
        s_w[t][3] = w * wy1 * wx1 * my1 * mx1;
    }
    __syncthreads();

    const int g = t >> 4;          // 0..15: (qi, h)
    const int lane = t & 15;       // channel pair
    const int qi = g >> 3, h = g & 7;
    const int bq = bq0 + qi;
    const int d2 = lane * 2;

    float accx = 0.f, accy = 0.f;
    const int pbase = qi * 128 + h * 16;
    #pragma unroll 8
    for (int i = 0; i < 16; i++) {
        int idx = pbase + i;
        #pragma unroll
        for (int c = 0; c < 4; c++) {
            int o = s_off[idx][c];
            float wgt = s_w[idx][c];
            unsigned u = *(const unsigned*)(v + o + d2);
            accx += wgt * __uint_as_float(u << 16);
            accy += wgt * __uint_as_float(u & 0xffff0000u);
        }
    }
    float2 res = make_float2(accx, accy);
    *(float2*)(out + (size_t)bq * 256 + h * 32 + d2) = res;
}

extern "C" void kernel_launch(void* const* d_in, const int* in_sizes, int n_in,
                              void* d_out, int out_size, void* d_ws, size_t ws_size,
                              hipStream_t stream) {
    const float* query     = (const float*)d_in[0];
    const float* value     = (const float*)d_in[1];
    const float* query_pos = (const float*)d_in[2];
    const float* refp      = (const float*)d_in[3];
    const float* W_val     = (const float*)d_in[4];
    const float* b_val     = (const float*)d_in[5];
    const float* W_off     = (const float*)d_in[6];
    const float* b_off     = (const float*)d_in[7];
    const float* W_attn    = (const float*)d_in[8];
    const float* b_attn    = (const float*)d_in[9];
    float* out = (float*)d_out;

    // Workspace layout (val_bf aliases off: val_bf dead before off is written)
    char* w = (char*)d_ws;
    float*  off     = (float*)w;
    ushort* val_bf  = (ushort*)w;            w += 20480000;  // max(off, val_bf)
    float*  attn    = (float*)w;             w += 10240000;
    ushort* qsum_bf = (ushort*)w;            w += 10240000;
    ushort* vp_bf   = (ushort*)w;            w += 20029440;  // planar (b,h,NV,32)
    ushort* Bt_hi   = (ushort*)w;            w += 327680;    // 640 x 256
    float*  bias_c  = (float*)w;             w += 2560;

    const int Mv = BS * NV;   // 39120
    const int Mq = BS * NQ;   // 20000

    convert_val<<<4890, 256, 0, stream>>>(value, val_bf);            // 39120*256/8
    convert_q<<<2500, 256, 0, stream>>>(query, query_pos, qsum_bf);  // 20000*256/8
    convert_W<<<640, 256, 0, stream>>>(W_val, W_off, W_attn, b_val, b_off, b_attn,
                                       Bt_hi, bias_c);

    dim3 gv((Mv + 127) / 128, 2);
    mfma_gemm2<false><<<gv, 256, 0, stream>>>(val_bf, Bt_hi, bias_c,
                                              vp_bf, nullptr, nullptr, Mv);
    dim3 gq((Mq + 127) / 128, 3);
    mfma_gemm2<true><<<gq, 256, 0, stream>>>(qsum_bf, Bt_hi + 256 * 256,
                                             bias_c + 256,
                                             nullptr, off, attn, Mq);
    sample3<<<BS * NQ / 2, 256, 0, stream>>>(vp_bf, off, attn, refp, out);
}

// Round 7
// 236.806 us; speedup vs baseline: 1.0901x; 1.0901x over previous
//
#include <hip/hip_runtime.h>

#define NQ 10000
#define BS 2
#define NV 19560
#define NH 8
#define HD 32
#define EMB 256

typedef __attribute__((ext_vector_type(8))) short bf16x8;
typedef __attribute__((ext_vector_type(4))) float f32x4;
typedef __attribute__((ext_vector_type(4))) short s16x4;

__device__ __forceinline__ unsigned short f2bf(float x) {
    unsigned u = __float_as_uint(x);
    u += 0x7FFFu + ((u >> 16) & 1u);       // RNE
    return (unsigned short)(u >> 16);
}

// ---------------------------------------------------------------------------
// Transpose weights into Bt[n][k] bf16 (rows 0-255 W_val, 256-511 W_off,
// 512-639 W_attn) + concat biases. Tiny one-shot kernel. [proven]
// ---------------------------------------------------------------------------
__global__ __launch_bounds__(256) void convert_W(
    const float* __restrict__ Wv, const float* __restrict__ Wo,
    const float* __restrict__ Wa, const float* __restrict__ bv,
    const float* __restrict__ bo, const float* __restrict__ ba,
    ushort* __restrict__ Bt, float* __restrict__ bias) {
    int n = blockIdx.x;      // 0..639
    int k = threadIdx.x;     // 0..255
    float x;
    if (n < 256)       x = Wv[k * 256 + n];
    else if (n < 512)  x = Wo[k * 256 + (n - 256)];
    else               x = Wa[k * 128 + (n - 512)];
    Bt[n * 256 + k] = f2bf(x);
    if (k == 0)
        bias[n] = (n < 256) ? bv[n] : (n < 512) ? bo[n - 256] : ba[n - 512];
}

// ---------------------------------------------------------------------------
// ONE fused GEMM dispatch for both projections (independent -> co-resident).
// blockIdx < 612: value-proj (m-block = bid>>1, n-panel = bid&1), planar bf16
// store. Else: query-proj (A = query+query_pos staged inline), fp32 off|attn.
// Structure = round-6 proven 128x128/BK=32 k-loop; A staged fp32->bf16 in LDS
// via the round-2-proven s16x4 construct (converts fused, hoisted kernels
// eliminated). B panel bf16 from Bt.
// ---------------------------------------------------------------------------
__global__ __launch_bounds__(256) void gemm_fused(
    const float* __restrict__ value, const float* __restrict__ query,
    const float* __restrict__ qpos, const ushort* __restrict__ Bt,
    const float* __restrict__ bias,
    ushort* __restrict__ Cv, float* __restrict__ C0, float* __restrict__ C1)
{
    __shared__ short As[128][40], Bhs[128][40];  // pad 32->40

    const int tid = threadIdx.x;
    const int bid = blockIdx.x;
    bool isval; int mblk, npan;
    if (bid < 612) { isval = true;  mblk = bid >> 1; npan = bid & 1; }
    else { int q = bid - 612; isval = false; mblk = q / 3; npan = q % 3; }

    const int M  = isval ? (BS * NV) : (BS * NQ);
    const int m0 = mblk * 128;
    const int n0 = npan * 128;
    const int nbase = (isval ? 0 : 256) + n0;   // global row in Bt / bias base

    const float* A  = isval ? value : query;

    const int arow = tid >> 1;
    const int acol = (tid & 1) * 16;
    const bool aval = (m0 + arow) < M;
    const float*  Ap  = A    + (size_t)(m0 + arow) * 256 + acol;
    const float*  A2p = qpos + (size_t)(m0 + arow) * 256 + acol;
    const ushort* Bp  = Bt   + (size_t)(nbase + arow) * 256 + acol;

    const int lane = tid & 63, wave = tid >> 6;
    const int wrow = (wave >> 1) * 64, wcol = (wave & 1) * 64;
    const int lr = lane & 15, quad = lane >> 4, lk = quad * 8;

    f32x4 acc[4][4] = {};

    for (int k0 = 0; k0 < 256; k0 += 32) {
        // ---- A: fp32 (+qpos) -> bf16 staged to LDS (round-2-proven form) ----
        #pragma unroll
        for (int g = 0; g < 4; g++) {
            f32x4 v = {};
            if (aval) {
                v = *(const f32x4*)(Ap + k0 + g * 4);
                if (!isval) v += *(const f32x4*)(A2p + k0 + g * 4);
            }
            s16x4 hh;
            #pragma unroll
            for (int e = 0; e < 4; e++) hh[e] = (short)f2bf(v[e]);
            *(s16x4*)&As[arow][acol + g * 4] = hh;
        }
        // ---- B: bf16 vector copy (round-6-proven) ----
        *(bf16x8*)&Bhs[arow][acol]     = *(const bf16x8*)(Bp + k0);
        *(bf16x8*)&Bhs[arow][acol + 8] = *(const bf16x8*)(Bp + k0 + 8);
        __syncthreads();

        bf16x8 af[4], bhf[4];
        #pragma unroll
        for (int i = 0; i < 4; i++)
            af[i] = *(const bf16x8*)&As[wrow + i * 16 + lr][lk];
        #pragma unroll
        for (int j = 0; j < 4; j++)
            bhf[j] = *(const bf16x8*)&Bhs[wcol + j * 16 + lr][lk];
        #pragma unroll
        for (int i = 0; i < 4; i++)
            #pragma unroll
            for (int j = 0; j < 4; j++)
                acc[i][j] = __builtin_amdgcn_mfma_f32_16x16x32_bf16(af[i], bhf[j], acc[i][j], 0, 0, 0);
        __syncthreads();
    }

    // ---- epilogue (round-6-proven mapping) ----
    #pragma unroll
    for (int j = 0; j < 4; j++) {
        int cc = wcol + j * 16 + lr;
        float bb = bias[nbase + cc];
        int col = n0 + cc;
        #pragma unroll
        for (int i = 0; i < 4; i++) {
            int gmb = m0 + wrow + i * 16 + quad * 4;
            #pragma unroll
            for (int r = 0; r < 4; r++) {
                int gm = gmb + r;
                if (gm < M) {
                    float val = acc[i][j][r] + bb;
                    if (isval) {
                        int h = col >> 5, d = col & 31;
                        int b = (gm >= NV) ? 1 : 0;
                        int pix = gm - b * NV;
                        Cv[((size_t)(b * 8 + h) * NV + pix) * 32 + d] = f2bf(val);
                    } else {
                        if (col < 256) C0[(size_t)gm * 256 + col] = val;
                        else           C1[(size_t)gm * 128 + (col - 256)] = val;
                    }
                }
            }
        }
    }
}

// ---------------------------------------------------------------------------
// Fused softmax + location + bilinear gather. Block = TWO (b,q), 256 threads.
// Phase 1 identical to proven sample3. Phase 2: 16 lanes per (q,h), lane =
// channel pair; explicit 16-wide register batches (o[16]/u[16]/wgt[16]) force
// 16 loads in flight (round-6 showed VGPR=16 -> compiler serialized loads);
// 4 split accumulators break the FMA dependency chain.
// ---------------------------------------------------------------------------
__global__ __launch_bounds__(256) void sample4(
    const ushort* __restrict__ v, const float* __restrict__ off,
    const float* __restrict__ attn, const float* __restrict__ refp,
    float* __restrict__ out)
{
    __shared__ int   s_off[256][5];
    __shared__ float s_w[256][5];

    const int bq0 = blockIdx.x * 2;
    const int t = threadIdx.x;

    {
        const int bq = bq0 + (t >> 7);
        const int b = (bq >= NQ) ? 1 : 0;
        const int i = t & 127;
        const int h = i >> 4, l = (i >> 2) & 3, p = i & 3;

        float logit = attn[(size_t)bq * 128 + i];
        float mx = logit;
        #pragma unroll
        for (int m = 1; m < 16; m <<= 1) mx = fmaxf(mx, __shfl_xor(mx, m, 16));
        float e = __expf(logit - mx);
        float s = e;
        #pragma unroll
        for (int m = 1; m < 16; m <<= 1) s += __shfl_xor(s, m, 16);
        float w = e / s;

        const float Wf[4] = {160.f, 80.f, 40.f, 20.f};
        const float Hf[4] = {92.f, 46.f, 23.f, 12.f};
        const int   Wi[4] = {160, 80, 40, 20};
        const int   Hi[4] = {92, 46, 23, 12};
        const int   st[4] = {0, 14720, 18400, 19320};

        float ox = off[(size_t)bq * 256 + h * 32 + l * 8 + p * 2];
        float oy = off[(size_t)bq * 256 + h * 32 + l * 8 + p * 2 + 1];
        float rx = refp[(size_t)bq * 8 + p * 2];
        float ry = refp[(size_t)bq * 8 + p * 2 + 1];
        float x = rx * Wf[l] + ox - 0.5f;
        float y = ry * Hf[l] + oy - 0.5f;
        float x0f = floorf(x), y0f = floorf(y);
        float wx1 = x - x0f, wy1 = y - y0f;
        float wx0 = 1.f - wx1, wy0 = 1.f - wy1;
        int x0 = (int)x0f, y0 = (int)y0f;
        const int W = Wi[l], H = Hi[l];
        float mx0 = ((unsigned)x0       < (unsigned)W) ? 1.f : 0.f;
        float mx1 = ((unsigned)(x0 + 1) < (unsigned)W) ? 1.f : 0.f;
        float my0 = ((unsigned)y0       < (unsigned)H) ? 1.f : 0.f;
        float my1 = ((unsigned)(y0 + 1) < (unsigned)H) ? 1.f : 0.f;
        int xc0 = min(max(x0, 0), W - 1);
        int xc1 = min(max(x0 + 1, 0), W - 1);
        int yc0 = min(max(y0, 0), H - 1);
        int yc1 = min(max(y0 + 1, 0), H - 1);
        int base = ((b * 8 + h) * NV + st[l]) * 32;
        s_off[t][0] = base + (yc0 * W + xc0) * 32;
        s_off[t][1] = base + (yc0 * W + xc1) * 32;
        s_off[t][2] = base + (yc1 * W + xc0) * 32;
        s_off[t][3] = base + (yc1 * W + xc1) * 32;
        s_w[t][0] = w * wy0 * wx0 * my0 * mx0;
        s_w[t][1] = w * wy0 * wx1 * my0 * mx1;
        s_w[t][2] = w * wy1 * wx0 * my1 * mx0;
        s_w[t][3] = w * wy1 * wx1 * my1 * mx1;
    }
    __syncthreads();

    const int g = t >> 4;          // 0..15: (qi, h)
    const int lane = t & 15;       // channel pair
    const int qi = g >> 3, h = g & 7;
    const int bq = bq0 + qi;
    const int d2 = lane * 2;
    const int pbase = qi * 128 + h * 16;

    float acc0 = 0.f, acc1 = 0.f, acc2 = 0.f, acc3 = 0.f;
    #pragma unroll
    for (int ib = 0; ib < 4; ib++) {
        int o[16]; float wgt[16];
        #pragma unroll
        for (int pp = 0; pp < 4; pp++) {
            int idx = pbase + ib * 4 + pp;
            #pragma unroll
            for (int c = 0; c < 4; c++) {
                o[pp * 4 + c]   = s_off[idx][c];
                wgt[pp * 4 + c] = s_w[idx][c];
            }
        }
        unsigned u[16];
        #pragma unroll
        for (int j = 0; j < 16; j++)
            u[j] = *(const unsigned*)(v + o[j] + d2);
        #pragma unroll
        for (int j = 0; j < 16; j += 2) {
            acc0 += wgt[j]     * __uint_as_float(u[j] << 16);
            acc1 += wgt[j]     * __uint_as_float(u[j] & 0xffff0000u);
            acc2 += wgt[j + 1] * __uint_as_float(u[j + 1] << 16);
            acc3 += wgt[j + 1] * __uint_as_float(u[j + 1] & 0xffff0000u);
        }
    }
    float2 res = make_float2(acc0 + acc2, acc1 + acc3);
    *(float2*)(out + (size_t)bq * 256 + h * 32 + d2) = res;
}

extern "C" void kernel_launch(void* const* d_in, const int* in_sizes, int n_in,
                              void* d_out, int out_size, void* d_ws, size_t ws_size,
                              hipStream_t stream) {
    const float* query     = (const float*)d_in[0];
    const float* value     = (const float*)d_in[1];
    const float* query_pos = (const float*)d_in[2];
    const float* refp      = (const float*)d_in[3];
    const float* W_val     = (const float*)d_in[4];
    const float* b_val     = (const float*)d_in[5];
    const float* W_off     = (const float*)d_in[6];
    const float* b_off     = (const float*)d_in[7];
    const float* W_attn    = (const float*)d_in[8];
    const float* b_attn    = (const float*)d_in[9];
    float* out = (float*)d_out;

    char* w = (char*)d_ws;
    float*  off    = (float*)w;   w += 20480000;   // 20000 x 256 fp32
    float*  attn   = (float*)w;   w += 10240000;   // 20000 x 128 fp32
    ushort* vp_bf  = (ushort*)w;  w += 20029440;   // planar (b,h,NV,32) bf16
    ushort* Bt     = (ushort*)w;  w += 327680;     // 640 x 256 bf16
    float*  bias_c = (float*)w;   w += 2560;

    convert_W<<<640, 256, 0, stream>>>(W_val, W_off, W_attn, b_val, b_off, b_attn,
                                       Bt, bias_c);

    // one dispatch: value-proj (612 blocks) + query-proj (471 blocks)
    gemm_fused<<<612 + 471, 256, 0, stream>>>(value, query, query_pos, Bt, bias_c,
                                              vp_bf, off, attn);

    // fused softmax + loc + bilinear sample (2 queries per block)
    sample4<<<BS * NQ / 2, 256, 0, stream>>>(vp_bf, off, attn, refp, out);
}

// Round 10
// 218.919 us; speedup vs baseline: 1.1792x; 1.0817x over previous
//
#include <hip/hip_runtime.h>

#define NQ 10000
#define BS 2
#define NV 19560
#define NH 8
#define HD 32
#define EMB 256

typedef __attribute__((ext_vector_type(8))) short bf16x8;
typedef __attribute__((ext_vector_type(4))) float f32x4;
typedef __attribute__((ext_vector_type(4))) short s16x4;

__device__ __forceinline__ unsigned short f2bf(float x) {
    unsigned u = __float_as_uint(x);
    u += 0x7FFFu + ((u >> 16) & 1u);       // RNE
    return (unsigned short)(u >> 16);
}

// ---------------------------------------------------------------------------
// Transpose weights into Bt[n][k] bf16 (rows 0-255 W_val, 256-511 W_off,
// 512-639 W_attn) + concat biases. Tiny one-shot kernel. [proven]
// ---------------------------------------------------------------------------
__global__ __launch_bounds__(256) void convert_W(
    const float* __restrict__ Wv, const float* __restrict__ Wo,
    const float* __restrict__ Wa, const float* __restrict__ bv,
    const float* __restrict__ bo, const float* __restrict__ ba,
    ushort* __restrict__ Bt, float* __restrict__ bias) {
    int n = blockIdx.x;      // 0..639
    int k = threadIdx.x;     // 0..255
    float x;
    if (n < 256)       x = Wv[k * 256 + n];
    else if (n < 512)  x = Wo[k * 256 + (n - 256)];
    else               x = Wa[k * 128 + (n - 512)];
    Bt[n * 256 + k] = f2bf(x);
    if (k == 0)
        bias[n] = (n < 256) ? bv[n] : (n < 512) ? bo[n - 256] : ba[n - 512];
}

// ---------------------------------------------------------------------------
// Fused GEMM, one dispatch for both projections. Round-7-proven 2-barrier
// k-loop, 64m x 128n tile (grid 2163 blocks ~8.5/CU -> co-resident blocks
// hide barrier drains, m114 overlap). 4 waves, wave tile 32m x 64n = 2x4 of
// 16x16x32 MFMAs. ROUND-9 BUG FIXED: B staging now writes BOTH bf16x8 halves
// (full 128x32 LDS coverage; r9 staged only half -> poison -> NaN).
// blockIdx < 1224: value-proj (mblk=bid>>1, npan=bid&1), planar bf16 store.
// Else: query-proj (A = query+query_pos staged inline), fp32 off|attn.
// ---------------------------------------------------------------------------
__global__ __launch_bounds__(256) void gemm_fused(
    const float* __restrict__ value, const float* __restrict__ query,
    const float* __restrict__ qpos, const ushort* __restrict__ Bt,
    const float* __restrict__ bias,
    ushort* __restrict__ Cv, float* __restrict__ C0, float* __restrict__ C1)
{
    __shared__ short As[64][40], Bhs[128][40];  // pad 32->40

    const int tid = threadIdx.x;
    const int bid = blockIdx.x;
    bool isval; int mblk, npan;
    if (bid < 1224) { isval = true;  mblk = bid >> 1; npan = bid & 1; }
    else { int q = bid - 1224; isval = false; mblk = q / 3; npan = q % 3; }

    const int M  = isval ? (BS * NV) : (BS * NQ);
    const int m0 = mblk * 64;
    const int n0 = npan * 128;
    const int nbase = (isval ? 0 : 256) + n0;

    const float* A = isval ? value : query;

    // A staging: thread t -> row t>>2 (0..63), k-chunk (t&3)*8 (8 of 32 k)
    const int arow = tid >> 2;
    const int acol = (tid & 3) * 8;
    const bool aval = (m0 + arow) < M;
    const float* Ap  = A    + (size_t)(m0 + arow) * 256 + acol;
    const float* A2p = qpos + (size_t)(m0 + arow) * 256 + acol;
    // B staging: thread t -> row t>>1 (0..127), k-half (t&1)*16 (16 of 32 k)
    const int brow = tid >> 1;
    const int bcol = (tid & 1) * 16;
    const ushort* Bp = Bt + (size_t)(nbase + brow) * 256 + bcol;

    const int lane = tid & 63, wave = tid >> 6;
    const int wrow = (wave >> 1) * 32, wcol = (wave & 1) * 64;
    const int lr = lane & 15, quad = lane >> 4, lk = quad * 8;

    f32x4 acc[2][4] = {};

    for (int k0 = 0; k0 < 256; k0 += 32) {
        // ---- A: fp32 (+qpos) -> bf16 staged to LDS (proven form) ----
        #pragma unroll
        for (int g = 0; g < 2; g++) {
            f32x4 v = {};
            if (aval) {
                v = *(const f32x4*)(Ap + k0 + g * 4);
                if (!isval) v += *(const f32x4*)(A2p + k0 + g * 4);
            }
            s16x4 hh;
            #pragma unroll
            for (int e = 0; e < 4; e++) hh[e] = (short)f2bf(v[e]);
            *(s16x4*)&As[arow][acol + g * 4] = hh;
        }
        // ---- B: bf16 vector copy, BOTH halves (16 shorts/thread) ----
        *(bf16x8*)&Bhs[brow][bcol]     = *(const bf16x8*)(Bp + k0);
        *(bf16x8*)&Bhs[brow][bcol + 8] = *(const bf16x8*)(Bp + k0 + 8);
        __syncthreads();

        bf16x8 af[2], bhf[4];
        #pragma unroll
        for (int i = 0; i < 2; i++)
            af[i] = *(const bf16x8*)&As[wrow + i * 16 + lr][lk];
        #pragma unroll
        for (int j = 0; j < 4; j++)
            bhf[j] = *(const bf16x8*)&Bhs[wcol + j * 16 + lr][lk];
        #pragma unroll
        for (int i = 0; i < 2; i++)
            #pragma unroll
            for (int j = 0; j < 4; j++)
                acc[i][j] = __builtin_amdgcn_mfma_f32_16x16x32_bf16(af[i], bhf[j], acc[i][j], 0, 0, 0);
        __syncthreads();
    }

    // ---- epilogue (proven mapping) ----
    #pragma unroll
    for (int j = 0; j < 4; j++) {
        int cc = wcol + j * 16 + lr;
        int col = n0 + cc;
        float bb = bias[nbase + cc];
        #pragma unroll
        for (int i = 0; i < 2; i++) {
            int gmb = m0 + wrow + i * 16 + quad * 4;
            #pragma unroll
            for (int r = 0; r < 4; r++) {
                int gm = gmb + r;
                if (gm < M) {
                    float val = acc[i][j][r] + bb;
                    if (isval) {
                        int h = col >> 5, d = col & 31;
                        int b = (gm >= NV) ? 1 : 0;
                        int pix = gm - b * NV;
                        Cv[((size_t)(b * 8 + h) * NV + pix) * 32 + d] = f2bf(val);
                    } else {
                        if (col < 256) C0[(size_t)gm * 256 + col] = val;
                        else           C1[(size_t)gm * 128 + (col - 256)] = val;
                    }
                }
            }
        }
    }
}

// ---------------------------------------------------------------------------
// Fused softmax + location + bilinear gather. [round-7 PROVEN, verbatim]
// Block = TWO (b,q), 256 threads. Phase 1: softmax + coords + corner offsets
// + premultiplied weights -> LDS. Phase 2: 16 lanes per (q,h), lane = channel
// pair; 16-wide register load batches; 4 split accumulators.
// ---------------------------------------------------------------------------
__global__ __launch_bounds__(256) void sample4(
    const ushort* __restrict__ v, const float* __restrict__ off,
    const float* __restrict__ attn, const float* __restrict__ refp,
    float* __restrict__ out)
{
    __shared__ int   s_off[256][5];
    __shared__ float s_w[256][5];

    const int bq0 = blockIdx.x * 2;
    const int t = threadIdx.x;

    {
        const int bq = bq0 + (t >> 7);
        const int b = (bq >= NQ) ? 1 : 0;
        const int i = t & 127;
        const int h = i >> 4, l = (i >> 2) & 3, p = i & 3;

        float logit = attn[(size_t)bq * 128 + i];
        float mx = logit;
        #pragma unroll
        for (int m = 1; m < 16; m <<= 1) mx = fmaxf(mx, __shfl_xor(mx, m, 16));
        float e = __expf(logit - mx);
        float s = e;
        #pragma unroll
        for (int m = 1; m < 16; m <<= 1) s += __shfl_xor(s, m, 16);
        float w = e / s;

        const float Wf[4] = {160.f, 80.f, 40.f, 20.f};
        const float Hf[4] = {92.f, 46.f, 23.f, 12.f};
        const int   Wi[4] = {160, 80, 40, 20};
        const int   Hi[4] = {92, 46, 23, 12};
        const int   st[4] = {0, 14720, 18400, 19320};

        float ox = off[(size_t)bq * 256 + h * 32 + l * 8 + p * 2];
        float oy = off[(size_t)bq * 256 + h * 32 + l * 8 + p * 2 + 1];
        float rx = refp[(size_t)bq * 8 + p * 2];
        float ry = refp[(size_t)bq * 8 + p * 2 + 1];
        float x = rx * Wf[l] + ox - 0.5f;
        float y = ry * Hf[l] + oy - 0.5f;
        float x0f = floorf(x), y0f = floorf(y);
        float wx1 = x - x0f, wy1 = y - y0f;
        float wx0 = 1.f - wx1, wy0 = 1.f - wy1;
        int x0 = (int)x0f, y0 = (int)y0f;
        const int W = Wi[l], H = Hi[l];
        float mx0 = ((unsigned)x0       < (unsigned)W) ? 1.f : 0.f;
        float mx1 = ((unsigned)(x0 + 1) < (unsigned)W) ? 1.f : 0.f;
        float my0 = ((unsigned)y0       < (unsigned)H) ? 1.f : 0.f;
        float my1 = ((unsigned)(y0 + 1) < (unsigned)H) ? 1.f : 0.f;
        int xc0 = min(max(x0, 0), W - 1);
        int xc1 = min(max(x0 + 1, 0), W - 1);
        int yc0 = min(max(y0, 0), H - 1);
        int yc1 = min(max(y0 + 1, 0), H - 1);
        int base = ((b * 8 + h) * NV + st[l]) * 32;
        s_off[t][0] = base + (yc0 * W + xc0) * 32;
        s_off[t][1] = base + (yc0 * W + xc1) * 32;
        s_off[t][2] = base + (yc1 * W + xc0) * 32;
        s_off[t][3] = base + (yc1 * W + xc1) * 32;
        s_w[t][0] = w * wy0 * wx0 * my0 * mx0;
        s_w[t][1] = w * wy0 * wx1 * my0 * mx1;
        s_w[t][2] = w * wy1 * wx0 * my1 * mx0;
        s_w[t][3] = w * wy1 * wx1 * my1 * mx1;
    }
    __syncthreads();

    const int g = t >> 4;          // 0..15: (qi, h)
    const int lane = t & 15;       // channel pair
    const int qi = g >> 3, h = g & 7;
    const int bq = bq0 + qi;
    const int d2 = lane * 2;
    const int pbase = qi * 128 + h * 16;

    float acc0 = 0.f, acc1 = 0.f, acc2 = 0.f, acc3 = 0.f;
    #pragma unroll
    for (int ib = 0; ib < 4; ib++) {
        int o[16]; float wgt[16];
        #pragma unroll
        for (int pp = 0; pp < 4; pp++) {
            int idx = pbase + ib * 4 + pp;
            #pragma unroll
            for (int c = 0; c < 4; c++) {
                o[pp * 4 + c]   = s_off[idx][c];
                wgt[pp * 4 + c] = s_w[idx][c];
            }
        }
        unsigned u[16];
        #pragma unroll
        for (int j = 0; j < 16; j++)
            u[j] = *(const unsigned*)(v + o[j] + d2);
        #pragma unroll
        for (int j = 0; j < 16; j += 2) {
            acc0 += wgt[j]     * __uint_as_float(u[j] << 16);
            acc1 += wgt[j]     * __uint_as_float(u[j] & 0xffff0000u);
            acc2 += wgt[j + 1] * __uint_as_float(u[j + 1] << 16);
            acc3 += wgt[j + 1] * __uint_as_float(u[j + 1] & 0xffff0000u);
        }
    }
    float2 res = make_float2(acc0 + acc2, acc1 + acc3);
    *(float2*)(out + (size_t)bq * 256 + h * 32 + d2) = res;
}

extern "C" void kernel_launch(void* const* d_in, const int* in_sizes, int n_in,
                              void* d_out, int out_size, void* d_ws, size_t ws_size,
                              hipStream_t stream) {
    const float* query     = (const float*)d_in[0];
    const float* value     = (const float*)d_in[1];
    const float* query_pos = (const float*)d_in[2];
    const float* refp      = (const float*)d_in[3];
    const float* W_val     = (const float*)d_in[4];
    const float* b_val     = (const float*)d_in[5];
    const float* W_off     = (const float*)d_in[6];
    const float* b_off     = (const float*)d_in[7];
    const float* W_attn    = (const float*)d_in[8];
    const float* b_attn    = (const float*)d_in[9];
    float* out = (float*)d_out;

    char* w = (char*)d_ws;
    float*  off    = (float*)w;   w += 20480000;   // 20000 x 256 fp32
    float*  attn   = (float*)w;   w += 10240000;   // 20000 x 128 fp32
    ushort* vp_bf  = (ushort*)w;  w += 20029440;   // planar (b,h,NV,32) bf16
    ushort* Bt     = (ushort*)w;  w += 327680;     // 640 x 256 bf16
    float*  bias_c = (float*)w;   w += 2560;

    convert_W<<<640, 256, 0, stream>>>(W_val, W_off, W_attn, b_val, b_off, b_attn,
                                       Bt, bias_c);

    // one dispatch: value-proj (1224 blocks) + query-proj (939 blocks)
    gemm_fused<<<1224 + 939, 256, 0, stream>>>(value, query, query_pos, Bt, bias_c,
                                               vp_bf, off, attn);

    // fused softmax + loc + bilinear sample (2 queries per block)
    sample4<<<BS * NQ / 2, 256, 0, stream>>>(vp_bf, off, attn, refp, out);
}